// Round 1
// baseline (257.153 us; speedup 1.0000x reference)
//
#include <hip/hip_runtime.h>
#include <cstdint>
#include <cstddef>

typedef _Float16 f16;
typedef _Float16 f16x8 __attribute__((ext_vector_type(8)));
typedef float f32x4 __attribute__((ext_vector_type(4)));

constexpr int Hh = 12;
constexpr int Tt = 2048;
constexpr int Dd = 64;
constexpr int Cc = 768;

// ---------------- fp32 -> fp16 convert, 8 elems/thread ----------------
__global__ __launch_bounds__(256)
void k_cvt(const float* __restrict__ src, f16* __restrict__ dst, int n8) {
  int i = blockIdx.x * 256 + threadIdx.x;
  if (i >= n8) return;
  const float4* s4 = (const float4*)src;
  float4 a = s4[2 * i], b = s4[2 * i + 1];
  f16x8 o = { (f16)a.x, (f16)a.y, (f16)a.z, (f16)a.w,
              (f16)b.x, (f16)b.y, (f16)b.z, (f16)b.w };
  *(f16x8*)(dst + (size_t)8 * i) = o;
}

// ---------------- async global->LDS 16B helper ----------------
__device__ __forceinline__ void async_cp16(const void* g, void* l) {
  __builtin_amdgcn_global_load_lds(
      (const __attribute__((address_space(1))) uint32_t*)(uintptr_t)g,
      (__attribute__((address_space(3))) uint32_t*)(uint32_t)(uintptr_t)l,
      16, 0, 0);
}

// ---------------- GEMM: C[m,n] = sum_k A[m,k]*B[n,k] + bias[n] ----------------
// EPI==0: scatter to Q/K/V fp16 [bh, t, d];  EPI==1: fp32 out [M,N]
template <int EPI>
__global__ __launch_bounds__(256)
void k_gemm(const f16* __restrict__ A, const f16* __restrict__ Bm,
            const float* __restrict__ bias, float* __restrict__ Cf,
            f16* __restrict__ Qd, f16* __restrict__ Kd, f16* __restrict__ Vd,
            int Nsz, int Ksz) {
  constexpr int BK = 32;
  __shared__ __align__(16) f16 As[128 * BK];
  __shared__ __align__(16) f16 Bs[128 * BK];
  const int tid = threadIdx.x;
  const int w = tid >> 6, l = tid & 63;
  const int ntn = Nsz >> 7;
  const int m0 = (blockIdx.x / ntn) << 7;
  const int n0 = (blockIdx.x % ntn) << 7;
  const int wm = (w >> 1) << 6, wn = (w & 1) << 6;
  const int lr = l >> 2;          // staging row within 16-row chunk
  const int lc = (l & 3) * 8;     // staging col
  const int fr = l & 15;          // fragment row/col
  const int fq = l >> 4;          // fragment k-quarter / row-group

  f32x4 acc[4][4] = {};

  for (int k0 = 0; k0 < Ksz; k0 += BK) {
    __syncthreads();
#pragma unroll
    for (int p = 0; p < 2; p++) {
      int chunk = w * 2 + p;
      int row = chunk * 16 + lr;
      async_cp16(&A[(size_t)(m0 + row) * Ksz + k0 + lc], &As[chunk * 512]);
      async_cp16(&Bm[(size_t)(n0 + row) * Ksz + k0 + lc], &Bs[chunk * 512]);
    }
    __syncthreads();
    f16x8 af[4], bf[4];
#pragma unroll
    for (int i = 0; i < 4; i++) {
      af[i] = *(const f16x8*)&As[(wm + i * 16 + fr) * BK + fq * 8];
      bf[i] = *(const f16x8*)&Bs[(wn + i * 16 + fr) * BK + fq * 8];
    }
#pragma unroll
    for (int i = 0; i < 4; i++)
#pragma unroll
      for (int j = 0; j < 4; j++)
        acc[i][j] = __builtin_amdgcn_mfma_f32_16x16x32_f16(af[i], bf[j], acc[i][j], 0, 0, 0);
  }

  if constexpr (EPI == 1) {
#pragma unroll
    for (int i = 0; i < 4; i++)
#pragma unroll
      for (int j = 0; j < 4; j++) {
        int col = n0 + wn + j * 16 + fr;
        float bv = bias[col];
#pragma unroll
        for (int jj = 0; jj < 4; jj++) {
          int row = m0 + wm + i * 16 + fq * 4 + jj;
          Cf[(size_t)row * Nsz + col] = acc[i][j][jj] + bv;
        }
      }
  } else {
    const int b = m0 >> 11;  // 128-row tile lies within one batch (2048 % 128 == 0)
#pragma unroll
    for (int j = 0; j < 4; j++) {
      int gcol = n0 + wn + j * 16 + fr;
      int which = gcol / Cc;
      int rem = gcol - which * Cc;
      int h = rem >> 6, d = rem & 63;
      f16* dst = which == 0 ? Qd : (which == 1 ? Kd : Vd);
      float bv = bias[gcol];
      size_t base = ((size_t)(b * Hh + h) * Tt) * Dd + d;
#pragma unroll
      for (int i = 0; i < 4; i++)
#pragma unroll
        for (int jj = 0; jj < 4; jj++) {
          int m = m0 + wm + i * 16 + fq * 4 + jj;
          int t = m & (Tt - 1);
          dst[base + (size_t)t * Dd] = (f16)(acc[i][j][jj] + bv);
        }
    }
  }
}

// ---------------- V transpose: [bh, t, d] -> [bh, d, t] ----------------
__global__ __launch_bounds__(256)
void k_trv(const f16* __restrict__ V, f16* __restrict__ Vt) {
  __shared__ __align__(16) f16 tile[64][72];
  int bh = blockIdx.x >> 5;           // T/64 = 32 tiles per bh
  int t0 = (blockIdx.x & 31) << 6;
  int tid = threadIdx.x;
#pragma unroll
  for (int p = 0; p < 2; p++) {
    int f = tid * 2 + p;
    int r = f >> 3, cc = (f & 7) * 8;
    *(f16x8*)&tile[r][cc] = *(const f16x8*)&V[((size_t)bh * Tt + t0 + r) * Dd + cc];
  }
  __syncthreads();
#pragma unroll
  for (int p = 0; p < 2; p++) {
    int f = tid * 2 + p;
    int d = f >> 3, cc = (f & 7) * 8;
    f16x8 v;
#pragma unroll
    for (int e = 0; e < 8; e++) v[e] = tile[cc + e][d];
    *(f16x8*)&Vt[((size_t)bh * Dd + d) * Tt + t0 + cc] = v;
  }
}

// ---------------- flash attention ----------------
// grid: bh(48) x qtile(16); 4 waves x 32 q-rows; KV tiles of 64
__global__ __launch_bounds__(256)
void k_attn(const f16* __restrict__ Q, const f16* __restrict__ Kd,
            const f16* __restrict__ Vt, f16* __restrict__ Ao) {
  __shared__ __align__(16) f16 Ks[64][72];
  __shared__ __align__(16) f16 Vs[64][72];        // rows = d, cols = kv offset
  __shared__ __align__(16) f16 Ps[4][32][72];     // per-wave P tile
  constexpr int NQ = Tt / 128;
  const int bh = blockIdx.x / NQ;
  const int q0 = (blockIdx.x % NQ) * 128;
  const int tid = threadIdx.x, w = tid >> 6, l = tid & 63;
  const int fr = l & 15, fq = l >> 4;
  const int qw = q0 + w * 32;
  const size_t kb = (size_t)bh * Tt * Dd;  // same base for K ([t,d]) and Vt ([d,t])

  f16x8 qf[2][2];
#pragma unroll
  for (int mi = 0; mi < 2; mi++)
#pragma unroll
    for (int kc = 0; kc < 2; kc++)
      qf[mi][kc] = *(const f16x8*)&Q[kb + (size_t)(qw + mi * 16 + fr) * Dd + kc * 32 + fq * 8];

  f32x4 o[2][4] = {};
  float mst[2][4], lst[2][4];
#pragma unroll
  for (int mi = 0; mi < 2; mi++)
#pragma unroll
    for (int jj = 0; jj < 4; jj++) { mst[mi][jj] = -1e30f; lst[mi][jj] = 0.f; }

  for (int kv0 = 0; kv0 < Tt; kv0 += 64) {
    __syncthreads();
#pragma unroll
    for (int p = 0; p < 2; p++) {
      int f = tid * 2 + p;
      int r = f >> 3, cc = (f & 7) * 8;
      *(f16x8*)&Ks[r][cc] = *(const f16x8*)&Kd[kb + (size_t)(kv0 + r) * Dd + cc];
      *(f16x8*)&Vs[r][cc] = *(const f16x8*)&Vt[kb + (size_t)r * Tt + kv0 + cc];
    }
    __syncthreads();

    // S = (Q K^T); C-layout: row q = fq*4+jj, col kv = fr (+16*ni)
    f32x4 s[2][4];
#pragma unroll
    for (int mi = 0; mi < 2; mi++)
#pragma unroll
      for (int ni = 0; ni < 4; ni++) {
        f32x4 a = {0.f, 0.f, 0.f, 0.f};
#pragma unroll
        for (int kc = 0; kc < 2; kc++) {
          f16x8 bk = *(const f16x8*)&Ks[ni * 16 + fr][kc * 32 + fq * 8];
          a = __builtin_amdgcn_mfma_f32_16x16x32_f16(qf[mi][kc], bk, a, 0, 0, 0);
        }
        s[mi][ni] = a;
      }
#pragma unroll
    for (int mi = 0; mi < 2; mi++)
#pragma unroll
      for (int ni = 0; ni < 4; ni++)
        s[mi][ni] *= 8.0f;  // faithful sqrt(HEAD_DIM) multiply

#pragma unroll
    for (int mi = 0; mi < 2; mi++) {
      float rm[4], mn[4], sf[4], rs[4];
#pragma unroll
      for (int jj = 0; jj < 4; jj++)
        rm[jj] = fmaxf(fmaxf(s[mi][0][jj], s[mi][1][jj]), fmaxf(s[mi][2][jj], s[mi][3][jj]));
#pragma unroll
      for (int msk = 1; msk < 16; msk <<= 1)
#pragma unroll
        for (int jj = 0; jj < 4; jj++)
          rm[jj] = fmaxf(rm[jj], __shfl_xor(rm[jj], msk, 64));
#pragma unroll
      for (int jj = 0; jj < 4; jj++) {
        mn[jj] = fmaxf(mst[mi][jj], rm[jj]);
        sf[jj] = __expf(mst[mi][jj] - mn[jj]);
        mst[mi][jj] = mn[jj];
        rs[jj] = 0.f;
      }
#pragma unroll
      for (int ni = 0; ni < 4; ni++)
#pragma unroll
        for (int jj = 0; jj < 4; jj++) {
          float p = __expf(s[mi][ni][jj] - mn[jj]);
          s[mi][ni][jj] = p;
          rs[jj] += p;
        }
#pragma unroll
      for (int msk = 1; msk < 16; msk <<= 1)
#pragma unroll
        for (int jj = 0; jj < 4; jj++)
          rs[jj] += __shfl_xor(rs[jj], msk, 64);
#pragma unroll
      for (int jj = 0; jj < 4; jj++) lst[mi][jj] = lst[mi][jj] * sf[jj] + rs[jj];
#pragma unroll
      for (int di = 0; di < 4; di++)
#pragma unroll
        for (int jj = 0; jj < 4; jj++) o[mi][di][jj] *= sf[jj];
      // P -> LDS (C-layout scatter); same-wave DS ops are in-order
#pragma unroll
      for (int ni = 0; ni < 4; ni++)
#pragma unroll
        for (int jj = 0; jj < 4; jj++)
          Ps[w][mi * 16 + fq * 4 + jj][ni * 16 + fr] = (f16)s[mi][ni][jj];
    }

    // O += P V
#pragma unroll
    for (int mi = 0; mi < 2; mi++)
#pragma unroll
      for (int kc = 0; kc < 2; kc++) {
        f16x8 ap = *(const f16x8*)&Ps[w][mi * 16 + fr][kc * 32 + fq * 8];
#pragma unroll
        for (int di = 0; di < 4; di++) {
          f16x8 bv = *(const f16x8*)&Vs[di * 16 + fr][kc * 32 + fq * 8];
          o[mi][di] = __builtin_amdgcn_mfma_f32_16x16x32_f16(ap, bv, o[mi][di], 0, 0, 0);
        }
      }
  }

  const int b = bh / Hh, h = bh - b * Hh;
#pragma unroll
  for (int mi = 0; mi < 2; mi++)
#pragma unroll
    for (int di = 0; di < 4; di++)
#pragma unroll
      for (int jj = 0; jj < 4; jj++) {
        int q = qw + mi * 16 + fq * 4 + jj;
        int d = di * 16 + fr;
        Ao[((size_t)b * Tt + q) * Cc + h * Dd + d] = (f16)(o[mi][di][jj] / lst[mi][jj]);
      }
}

// ---------------- launch ----------------
extern "C" void kernel_launch(void* const* d_in, const int* in_sizes, int n_in,
                              void* d_out, int out_size, void* d_ws, size_t ws_size,
                              hipStream_t stream) {
  const float* x    = (const float*)d_in[0];
  const float* qkvw = (const float*)d_in[1];
  const float* qkvb = (const float*)d_in[2];
  const float* pw   = (const float*)d_in[3];
  const float* pb   = (const float*)d_in[4];
  float* out = (float*)d_out;

  char* wsp = (char*)d_ws;
  f16* xb  = (f16*)(wsp);                                   // 12582912 B
  f16* wqb = (f16*)(wsp + 12582912);                        //  3538944 B
  f16* wpb = (f16*)(wsp + 12582912 + 3538944);              //  1179648 B
  f16* Qb  = (f16*)(wsp + 12582912 + 3538944 + 1179648);    // 12582912 B
  f16* Kb  = (f16*)((char*)Qb + 12582912);                  // 12582912 B
  f16* Vb  = (f16*)((char*)Kb + 12582912);                  // 12582912 B
  f16* Vt  = xb;   // xb dead after QKV GEMM
  f16* Ao  = Vb;   // Vb dead after transpose

  k_cvt<<<3072, 256, 0, stream>>>(x, xb, 786432);
  k_cvt<<<864, 256, 0, stream>>>(qkvw, wqb, 221184);
  k_cvt<<<288, 256, 0, stream>>>(pw, wpb, 73728);
  k_gemm<0><<<(8192 / 128) * (2304 / 128), 256, 0, stream>>>(xb, wqb, qkvb, nullptr,
                                                             Qb, Kb, Vb, 2304, 768);
  k_trv<<<48 * 32, 256, 0, stream>>>(Vb, Vt);
  k_attn<<<48 * 16, 256, 0, stream>>>(Qb, Kb, Vt, Ao);
  k_gemm<1><<<(8192 / 128) * (768 / 128), 256, 0, stream>>>(Ao, wpb, pb, out,
                                                            nullptr, nullptr, nullptr, 768, 768);
}